// Round 1
// baseline (1551.857 us; speedup 1.0000x reference)
//
#include <hip/hip_runtime.h>
#include <cstddef>

#define NN 50000
#define NE 800000
#define D 128
#define NG 512
#define BN_EPS 1e-5f

// ---- workspace layout (float offsets) ----
#define OFF_DEG   0            // int[50000] (uses 50048 float slots)
#define OFF_ACCN  50048        // float[4*512]: key, env, nz, cnt
#define OFF_ACCE  52096        // float[4*512]
#define ZERO_FLOATS 54144      // everything below here is zeroed each call
#define OFF_DIS   54144        // float[50000]
#define OFF_T1    104192       // float[50000]
#define OFF_T2    154240       // float[50000]
#define OFF_WP    204288       // float[3*128*128] folded weights
#define OFF_BP    253440       // float[3*128]   folded biases
#define OFF_HA    253952       // float[50000*128]
#define OFF_HB    6653952      // float[50000*128]

// ---- output layout (float offsets in d_out) ----
#define O_NKEY 0
#define O_EKEY 50000
#define O_NKN  850000
#define O_NEN  850512
#define O_EKN  851024
#define O_EEN  851536
#define O_NZN  852048
#define O_NZE  852560

__device__ __forceinline__ float sigmoidf(float x) {
    return 1.0f / (1.0f + expf(-x));
}

// Fold BN into weights: Wp[l][k][j] = a[k]*W[l][k][j]; bp[l][j] = sum_k c[k]*W[l][k][j]
__global__ void prep_w(const float* __restrict__ W, const float* __restrict__ gamma,
                       const float* __restrict__ beta, const float* __restrict__ mean,
                       const float* __restrict__ var, float* __restrict__ Wp,
                       float* __restrict__ bp) {
    int l = blockIdx.x;
    int j = threadIdx.x;
    float acc = 0.f;
    for (int k = 0; k < D; ++k) {
        float a = gamma[l * D + k] * rsqrtf(var[l * D + k] + BN_EPS);
        float c = beta[l * D + k] - mean[l * D + k] * a;
        float w = W[l * D * D + k * D + j];
        Wp[l * D * D + k * D + j] = a * w;
        acc = fmaf(c, w, acc);
    }
    bp[l * D + j] = acc;
}

__global__ void deg_kernel(const int* __restrict__ ei, int* __restrict__ deg) {
    int e = blockIdx.x * 256 + threadIdx.x;
    if (e < NE) atomicAdd(&deg[ei[e]], 1);
}

__global__ void dis_kernel(const int* __restrict__ deg, float* __restrict__ dis) {
    int n = blockIdx.x * 256 + threadIdx.x;
    if (n < NN) dis[n] = rsqrtf((float)(deg[n] + 1));  // +1 self loop
}

// out[64 rows x 128 cols] = act( A @ B + bias ), optional pre-transform on A load.
template <bool PRE, bool ORELU>
__global__ __launch_bounds__(256) void gemm128(const float* __restrict__ A,
                                               const float* __restrict__ B,
                                               const float* __restrict__ bias,
                                               const float* __restrict__ pre,
                                               float* __restrict__ out) {
    __shared__ float As[64][129];
    const int tid = threadIdx.x;
    const int row0 = blockIdx.x * 64;

    // stage A tile (with optional relu(x+pre) transform)
    for (int t = 0; t < 8; ++t) {
        int i4 = tid + t * 256;          // float4 index in 64x128 tile
        int r = i4 >> 5;
        int c4 = (i4 & 31) * 4;
        int gr = row0 + r;
        float4 v = make_float4(0.f, 0.f, 0.f, 0.f);
        if (gr < NN) v = *(const float4*)(A + (size_t)gr * D + c4);
        if (PRE) {
            v.x = fmaxf(v.x + pre[c4 + 0], 0.f);
            v.y = fmaxf(v.y + pre[c4 + 1], 0.f);
            v.z = fmaxf(v.z + pre[c4 + 2], 0.f);
            v.w = fmaxf(v.w + pre[c4 + 3], 0.f);
        }
        As[r][c4 + 0] = v.x;
        As[r][c4 + 1] = v.y;
        As[r][c4 + 2] = v.z;
        As[r][c4 + 3] = v.w;
    }
    __syncthreads();

    const int cg = tid & 15;   // 16 col-groups of 8
    const int rg = tid >> 4;   // 16 row-groups of 4
    const int c0 = cg * 8;
    const int r0 = rg * 4;

    float acc[4][8];
#pragma unroll
    for (int i = 0; i < 4; ++i)
#pragma unroll
        for (int j = 0; j < 8; ++j) acc[i][j] = 0.f;

#pragma unroll 4
    for (int k = 0; k < 128; ++k) {
        const float4 b0 = *(const float4*)(B + k * D + c0);
        const float4 b1 = *(const float4*)(B + k * D + c0 + 4);
#pragma unroll
        for (int i = 0; i < 4; ++i) {
            const float a = As[r0 + i][k];
            acc[i][0] = fmaf(a, b0.x, acc[i][0]);
            acc[i][1] = fmaf(a, b0.y, acc[i][1]);
            acc[i][2] = fmaf(a, b0.z, acc[i][2]);
            acc[i][3] = fmaf(a, b0.w, acc[i][3]);
            acc[i][4] = fmaf(a, b1.x, acc[i][4]);
            acc[i][5] = fmaf(a, b1.y, acc[i][5]);
            acc[i][6] = fmaf(a, b1.z, acc[i][6]);
            acc[i][7] = fmaf(a, b1.w, acc[i][7]);
        }
    }

    const float4 bb0 = *(const float4*)(bias + c0);
    const float4 bb1 = *(const float4*)(bias + c0 + 4);
#pragma unroll
    for (int i = 0; i < 4; ++i) {
        int gr = row0 + r0 + i;
        if (gr < NN) {
            float4 o0 = make_float4(acc[i][0] + bb0.x, acc[i][1] + bb0.y,
                                    acc[i][2] + bb0.z, acc[i][3] + bb0.w);
            float4 o1 = make_float4(acc[i][4] + bb1.x, acc[i][5] + bb1.y,
                                    acc[i][6] + bb1.z, acc[i][7] + bb1.w);
            if (ORELU) {
                o0.x = fmaxf(o0.x, 0.f); o0.y = fmaxf(o0.y, 0.f);
                o0.z = fmaxf(o0.z, 0.f); o0.w = fmaxf(o0.w, 0.f);
                o1.x = fmaxf(o1.x, 0.f); o1.y = fmaxf(o1.y, 0.f);
                o1.z = fmaxf(o1.z, 0.f); o1.w = fmaxf(o1.w, 0.f);
            }
            *(float4*)(out + (size_t)gr * D + c0) = o0;
            *(float4*)(out + (size_t)gr * D + c0 + 4) = o1;
        }
    }
}

// hout[n] = dis[n]^2 * hin[n]   (self-loop term; also zero-initializes accumulator)
__global__ __launch_bounds__(256) void prop_init(const float* __restrict__ dis,
                                                 const float* __restrict__ hin,
                                                 float* __restrict__ hout) {
    int total = NN * 32;  // float4 count
    for (int idx = blockIdx.x * 256 + threadIdx.x; idx < total; idx += gridDim.x * 256) {
        int n = idx >> 5;
        float d = dis[n];
        float s = d * d;
        float4 v = ((const float4*)hin)[idx];
        v.x *= s; v.y *= s; v.z *= s; v.w *= s;
        ((float4*)hout)[idx] = v;
    }
}

// hout[col] += dis[row]*dis[col]*hin[row], one wave per edge
__global__ __launch_bounds__(256) void prop_edges(const int* __restrict__ ei,
                                                  const float* __restrict__ dis,
                                                  const float* __restrict__ hin,
                                                  float* __restrict__ hout) {
    int wid = (blockIdx.x * 256 + threadIdx.x) >> 6;
    int lane = threadIdx.x & 63;
    int nw = (gridDim.x * 256) >> 6;
    for (int e = wid; e < NE; e += nw) {
        int r = ei[e];
        int c = ei[NE + e];
        float nrm = dis[r] * dis[c];
        float2 v = ((const float2*)(hin + (size_t)r * D))[lane];
        float* dst = hout + (size_t)c * D + lane * 2;
        unsafeAtomicAdd(dst, v.x * nrm);
        unsafeAtomicAdd(dst + 1, v.y * nrm);
    }
}

// node head: node_key, t1/t2 edge partial dots, node-side segment bins
__global__ __launch_bounds__(256) void node_kernel(
    const float* __restrict__ h, const float* __restrict__ bh1,
    const float* __restrict__ We, const float* __restrict__ Wn,
    const float* __restrict__ bnb, const int* __restrict__ batch,
    float* __restrict__ nkey_out, float* __restrict__ t1, float* __restrict__ t2,
    float* __restrict__ accN) {
    __shared__ float binK[NG], binE[NG], binZ[NG], binC[NG];
    const int tid = threadIdx.x;
    for (int i = tid; i < NG; i += 256) { binK[i] = 0.f; binE[i] = 0.f; binZ[i] = 0.f; binC[i] = 0.f; }
    __syncthreads();

    const int CHUNK = 98;  // 512*98 >= 50000
    int start = blockIdx.x * CHUNK;
    int end = min(start + CHUNK, NN);
    int wid = tid >> 6, lane = tid & 63;
    float bnb0 = bnb[0];

    float2 w1 = ((const float2*)We)[lane];
    float2 w2 = ((const float2*)(We + D))[lane];
    float2 wn = ((const float2*)Wn)[lane];
    float2 bb = ((const float2*)bh1)[lane];

    for (int n = start + wid; n < end; n += 4) {
        float2 v = ((const float2*)(h + (size_t)n * D))[lane];
        v.x += bb.x; v.y += bb.y;
        float s1 = v.x * w1.x + v.y * w1.y;
        float s2 = v.x * w2.x + v.y * w2.y;
        float s3 = v.x * wn.x + v.y * wn.y;
        for (int o = 32; o; o >>= 1) {
            s1 += __shfl_xor(s1, o);
            s2 += __shfl_xor(s2, o);
            s3 += __shfl_xor(s3, o);
        }
        if (lane == 0) {
            t1[n] = s1;
            t2[n] = s2;
            float nk = sigmoidf(s3 + bnb0);
            nkey_out[n] = nk;
            int g = batch[n];
            atomicAdd(&binK[g], nk);
            atomicAdd(&binE[g], 1.0f - nk);
            if (nk > 0.f) atomicAdd(&binZ[g], 1.0f);
            atomicAdd(&binC[g], 1.0f);
        }
    }
    __syncthreads();
    if (start < NN) {
        int glo = batch[start];
        int ghi = batch[end - 1];
        for (int g = glo + tid; g <= ghi; g += 256) {
            atomicAdd(&accN[g], binK[g]);
            atomicAdd(&accN[NG + g], binE[g]);
            atomicAdd(&accN[2 * NG + g], binZ[g]);
            atomicAdd(&accN[3 * NG + g], binC[g]);
        }
    }
}

// edge head: edge_key + edge-side segment bins
__global__ __launch_bounds__(256) void edge_kernel(
    const int* __restrict__ ei, const float* __restrict__ t1,
    const float* __restrict__ t2, const float* __restrict__ be,
    const int* __restrict__ batch, float* __restrict__ ekey_out,
    float* __restrict__ accE) {
    __shared__ float binK[NG], binE[NG], binZ[NG], binC[NG];
    const int tid = threadIdx.x;
    for (int i = tid; i < NG; i += 256) { binK[i] = 0.f; binE[i] = 0.f; binZ[i] = 0.f; binC[i] = 0.f; }
    __syncthreads();
    float be0 = be[0];
    int stride = gridDim.x * 256;
    for (int e = blockIdx.x * 256 + tid; e < NE; e += stride) {
        int r = ei[e];
        int c = ei[NE + e];
        float ek = sigmoidf(t1[r] + t2[c] + be0);
        ekey_out[e] = ek;
        int g = batch[r];
        atomicAdd(&binK[g], ek);
        atomicAdd(&binE[g], 1.0f - ek);
        if (ek > 0.f) atomicAdd(&binZ[g], 1.0f);
        atomicAdd(&binC[g], 1.0f);
    }
    __syncthreads();
    for (int g = tid; g < NG; g += 256) {
        if (binC[g] != 0.f) {
            atomicAdd(&accE[g], binK[g]);
            atomicAdd(&accE[NG + g], binE[g]);
            atomicAdd(&accE[2 * NG + g], binZ[g]);
            atomicAdd(&accE[3 * NG + g], binC[g]);
        }
    }
}

__global__ void final_kernel(const float* __restrict__ accN,
                             const float* __restrict__ accE,
                             float* __restrict__ out) {
    int g = blockIdx.x * 256 + threadIdx.x;
    if (g < NG) {
        out[O_NKN + g] = accN[g] + 1e-8f;
        out[O_NEN + g] = accN[NG + g] + 1e-8f;
        out[O_EKN + g] = accE[g] + 1e-8f;
        out[O_EEN + g] = accE[NG + g] + 1e-8f;
        out[O_NZN + g] = accN[2 * NG + g] / accN[3 * NG + g];
        out[O_NZE + g] = accE[2 * NG + g] / accE[3 * NG + g];
    }
}

extern "C" void kernel_launch(void* const* d_in, const int* in_sizes, int n_in,
                              void* d_out, int out_size, void* d_ws, size_t ws_size,
                              hipStream_t stream) {
    const float* x     = (const float*)d_in[0];
    const int*   ei    = (const int*)d_in[1];
    const int*   batch = (const int*)d_in[2];
    // d_in[3] = num_graphs (512), hardcoded
    const float* W     = (const float*)d_in[4];
    const float* bh    = (const float*)d_in[5];   // [2][128]
    const float* gamma = (const float*)d_in[6];
    const float* beta  = (const float*)d_in[7];
    const float* mean  = (const float*)d_in[8];
    const float* var   = (const float*)d_in[9];
    const float* We    = (const float*)d_in[10];  // [256]
    const float* be    = (const float*)d_in[11];
    const float* Wn    = (const float*)d_in[12];  // [128]
    const float* bnb   = (const float*)d_in[13];

    float* ws  = (float*)d_ws;
    float* out = (float*)d_out;

    int*   deg  = (int*)(ws + OFF_DEG);
    float* accN = ws + OFF_ACCN;
    float* accE = ws + OFF_ACCE;
    float* dis  = ws + OFF_DIS;
    float* t1   = ws + OFF_T1;
    float* t2   = ws + OFF_T2;
    float* Wp   = ws + OFF_WP;
    float* bp   = ws + OFF_BP;
    float* hA   = ws + OFF_HA;
    float* hB   = ws + OFF_HB;

    hipMemsetAsync(d_ws, 0, (size_t)ZERO_FLOATS * sizeof(float), stream);

    prep_w<<<3, 128, 0, stream>>>(W, gamma, beta, mean, var, Wp, bp);
    deg_kernel<<<(NE + 255) / 256, 256, 0, stream>>>(ei, deg);
    dis_kernel<<<(NN + 255) / 256, 256, 0, stream>>>(deg, dis);

    // layer 0: hA = relu(x @ Wp0 + bp0)
    gemm128<false, true><<<782, 256, 0, stream>>>(x, Wp, bp, nullptr, hA);
    // layer 1 linear: hB = hA @ Wp1 + bp1
    gemm128<false, false><<<782, 256, 0, stream>>>(hA, Wp + D * D, bp + D, nullptr, hB);
    // propagate 1: hA = P(hB)
    prop_init<<<2048, 256, 0, stream>>>(dis, hB, hA);
    prop_edges<<<8192, 256, 0, stream>>>(ei, dis, hB, hA);
    // layer 2 linear with fused relu(h + b_hidden[0]) on input: hB = relu(hA+bh0) @ Wp2 + bp2
    gemm128<true, false><<<782, 256, 0, stream>>>(hA, Wp + 2 * D * D, bp + 2 * D, bh, hB);
    // propagate 2: hA = P(hB)
    prop_init<<<2048, 256, 0, stream>>>(dis, hB, hA);
    prop_edges<<<8192, 256, 0, stream>>>(ei, dis, hB, hA);

    // heads (node_rep = hA + b_hidden[1], applied inline)
    node_kernel<<<512, 256, 0, stream>>>(hA, bh + D, We, Wn, bnb, batch,
                                         out + O_NKEY, t1, t2, accN);
    edge_kernel<<<256, 256, 0, stream>>>(ei, t1, t2, be, batch, out + O_EKEY, accE);
    final_kernel<<<2, 256, 0, stream>>>(accN, accE, out);
}

// Round 2
// 463.688 us; speedup vs baseline: 3.3468x; 3.3468x over previous
//
#include <hip/hip_runtime.h>
#include <cstddef>

#define NN 50000
#define NE 800000
#define D 128
#define NG 512
#define BN_EPS 1e-5f

// ---- workspace layout (float offsets) ----
#define OFF_DEG   0            // int[50000] row (out) degree
#define OFF_CNT   50048        // int[50000] col (in) degree
#define OFF_ACCN  100096       // float[4*512]: key, env, nz, cnt
#define OFF_ACCE  102144       // float[4*512]
#define ZERO_FLOATS 104192     // everything below here is zeroed each call
#define OFF_DIS   104192       // float[50000]
#define OFF_COLP  154240       // int[50000] CSR col starts (exclusive scan)
#define OFF_CUR   204288       // int[50000] fill cursors (== ends after fill)
#define OFF_BSUM  254336       // int[256]
#define OFF_BOFF  254592       // int[256]
#define OFF_T1    254848       // float[50000]
#define OFF_T2    304896       // float[50000]
#define OFF_WP    354944       // float[3*128*128] folded weights
#define OFF_BP    404096       // float[3*128] (padded)
#define OFF_SRCS  404608       // int[800000] CSR source node ids
#define OFF_HA    1204608      // float[50000*128]
#define OFF_HB    7604608      // float[50000*128]

// ---- output layout (float offsets in d_out) ----
#define O_NKEY 0
#define O_EKEY 50000
#define O_NKN  850000
#define O_NEN  850512
#define O_EKN  851024
#define O_EEN  851536
#define O_NZN  852048
#define O_NZE  852560

__device__ __forceinline__ float sigmoidf(float x) {
    return 1.0f / (1.0f + expf(-x));
}

// Fold BN into weights: Wp[l][k][j] = a[k]*W[l][k][j]; bp[l][j] = sum_k c[k]*W[l][k][j]
__global__ void prep_w(const float* __restrict__ W, const float* __restrict__ gamma,
                       const float* __restrict__ beta, const float* __restrict__ mean,
                       const float* __restrict__ var, float* __restrict__ Wp,
                       float* __restrict__ bp) {
    int l = blockIdx.x;
    int j = threadIdx.x;
    float acc = 0.f;
    for (int k = 0; k < D; ++k) {
        float a = gamma[l * D + k] * rsqrtf(var[l * D + k] + BN_EPS);
        float c = beta[l * D + k] - mean[l * D + k] * a;
        float w = W[l * D * D + k * D + j];
        Wp[l * D * D + k * D + j] = a * w;
        acc = fmaf(c, w, acc);
    }
    bp[l * D + j] = acc;
}

// out-degree (for dis) and in-degree (for CSR) in one pass
__global__ void degcnt_kernel(const int* __restrict__ ei, int* __restrict__ deg,
                              int* __restrict__ cnt) {
    int e = blockIdx.x * 256 + threadIdx.x;
    if (e < NE) {
        atomicAdd(&deg[ei[e]], 1);
        atomicAdd(&cnt[ei[NE + e]], 1);
    }
}

__global__ void dis_kernel(const int* __restrict__ deg, float* __restrict__ dis) {
    int n = blockIdx.x * 256 + threadIdx.x;
    if (n < NN) dis[n] = rsqrtf((float)(deg[n] + 1));  // +1 self loop
}

// ---- 3-phase exclusive scan of cnt -> colptr ----
__global__ void scan1(const int* __restrict__ cnt, int* __restrict__ colp,
                      int* __restrict__ bsum) {
    __shared__ int s[256];
    int t = threadIdx.x;
    int i = blockIdx.x * 256 + t;
    int v = (i < NN) ? cnt[i] : 0;
    s[t] = v;
    __syncthreads();
    for (int o = 1; o < 256; o <<= 1) {
        int add = (t >= o) ? s[t - o] : 0;
        __syncthreads();
        s[t] += add;
        __syncthreads();
    }
    if (i < NN) colp[i] = s[t] - v;   // local exclusive
    if (t == 255) bsum[blockIdx.x] = s[255];
}

__global__ void scan2(const int* __restrict__ bsum, int* __restrict__ boff, int nb) {
    __shared__ int s[256];
    int t = threadIdx.x;
    int v = (t < nb) ? bsum[t] : 0;
    s[t] = v;
    __syncthreads();
    for (int o = 1; o < 256; o <<= 1) {
        int add = (t >= o) ? s[t - o] : 0;
        __syncthreads();
        s[t] += add;
        __syncthreads();
    }
    boff[t] = s[t] - v;  // exclusive
}

__global__ void scan3(int* __restrict__ colp, const int* __restrict__ boff,
                      int* __restrict__ cur) {
    int i = blockIdx.x * 256 + threadIdx.x;
    if (i < NN) {
        int v = colp[i] + boff[i >> 8];
        colp[i] = v;
        cur[i] = v;
    }
}

// scatter edge sources into per-column buckets
__global__ void fill_kernel(const int* __restrict__ ei, int* __restrict__ cur,
                            int* __restrict__ srcs) {
    int e = blockIdx.x * 256 + threadIdx.x;
    if (e < NE) {
        int r = ei[e];
        int c = ei[NE + e];
        int pos = atomicAdd(&cur[c], 1);
        srcs[pos] = r;
    }
}

// out[64 rows x 128 cols] = act( A @ B + bias ), optional pre-transform on A load.
template <bool PRE, bool ORELU>
__global__ __launch_bounds__(256) void gemm128(const float* __restrict__ A,
                                               const float* __restrict__ B,
                                               const float* __restrict__ bias,
                                               const float* __restrict__ pre,
                                               float* __restrict__ out) {
    __shared__ float As[64][129];
    const int tid = threadIdx.x;
    const int row0 = blockIdx.x * 64;

    for (int t = 0; t < 8; ++t) {
        int i4 = tid + t * 256;          // float4 index in 64x128 tile
        int r = i4 >> 5;
        int c4 = (i4 & 31) * 4;
        int gr = row0 + r;
        float4 v = make_float4(0.f, 0.f, 0.f, 0.f);
        if (gr < NN) v = *(const float4*)(A + (size_t)gr * D + c4);
        if (PRE) {
            v.x = fmaxf(v.x + pre[c4 + 0], 0.f);
            v.y = fmaxf(v.y + pre[c4 + 1], 0.f);
            v.z = fmaxf(v.z + pre[c4 + 2], 0.f);
            v.w = fmaxf(v.w + pre[c4 + 3], 0.f);
        }
        As[r][c4 + 0] = v.x;
        As[r][c4 + 1] = v.y;
        As[r][c4 + 2] = v.z;
        As[r][c4 + 3] = v.w;
    }
    __syncthreads();

    const int cg = tid & 15;
    const int rg = tid >> 4;
    const int c0 = cg * 8;
    const int r0 = rg * 4;

    float acc[4][8];
#pragma unroll
    for (int i = 0; i < 4; ++i)
#pragma unroll
        for (int j = 0; j < 8; ++j) acc[i][j] = 0.f;

#pragma unroll 4
    for (int k = 0; k < 128; ++k) {
        const float4 b0 = *(const float4*)(B + k * D + c0);
        const float4 b1 = *(const float4*)(B + k * D + c0 + 4);
#pragma unroll
        for (int i = 0; i < 4; ++i) {
            const float a = As[r0 + i][k];
            acc[i][0] = fmaf(a, b0.x, acc[i][0]);
            acc[i][1] = fmaf(a, b0.y, acc[i][1]);
            acc[i][2] = fmaf(a, b0.z, acc[i][2]);
            acc[i][3] = fmaf(a, b0.w, acc[i][3]);
            acc[i][4] = fmaf(a, b1.x, acc[i][4]);
            acc[i][5] = fmaf(a, b1.y, acc[i][5]);
            acc[i][6] = fmaf(a, b1.z, acc[i][6]);
            acc[i][7] = fmaf(a, b1.w, acc[i][7]);
        }
    }

    const float4 bb0 = *(const float4*)(bias + c0);
    const float4 bb1 = *(const float4*)(bias + c0 + 4);
#pragma unroll
    for (int i = 0; i < 4; ++i) {
        int gr = row0 + r0 + i;
        if (gr < NN) {
            float4 o0 = make_float4(acc[i][0] + bb0.x, acc[i][1] + bb0.y,
                                    acc[i][2] + bb0.z, acc[i][3] + bb0.w);
            float4 o1 = make_float4(acc[i][4] + bb1.x, acc[i][5] + bb1.y,
                                    acc[i][6] + bb1.z, acc[i][7] + bb1.w);
            if (ORELU) {
                o0.x = fmaxf(o0.x, 0.f); o0.y = fmaxf(o0.y, 0.f);
                o0.z = fmaxf(o0.z, 0.f); o0.w = fmaxf(o0.w, 0.f);
                o1.x = fmaxf(o1.x, 0.f); o1.y = fmaxf(o1.y, 0.f);
                o1.z = fmaxf(o1.z, 0.f); o1.w = fmaxf(o1.w, 0.f);
            }
            *(float4*)(out + (size_t)gr * D + c0) = o0;
            *(float4*)(out + (size_t)gr * D + c0 + 4) = o1;
        }
    }
}

// gather-form GCN propagate: one wave per destination node, no atomics.
// out[n] = dis[n] * ( dis[n]*hin[n] + sum_{s in in(n)} dis[s]*hin[s] )
__global__ __launch_bounds__(256) void prop_gather(
    const int* __restrict__ colp, const int* __restrict__ cur,
    const int* __restrict__ srcs, const float* __restrict__ dis,
    const float* __restrict__ hin, float* __restrict__ hout) {
    int wid = (blockIdx.x * 256 + threadIdx.x) >> 6;
    int lane = threadIdx.x & 63;
    if (wid >= NN) return;
    const int n = wid;
    const int start = colp[n];
    const int end = cur[n];      // cursor == bucket end after fill
    const float dn = dis[n];
    float2 v = ((const float2*)(hin + (size_t)n * D))[lane];
    float ax = dn * v.x, ay = dn * v.y;
    int i = start;
    for (; i + 1 < end; i += 2) {
        int s0 = srcs[i], s1 = srcs[i + 1];
        float w0 = dis[s0], w1 = dis[s1];
        float2 u0 = ((const float2*)(hin + (size_t)s0 * D))[lane];
        float2 u1 = ((const float2*)(hin + (size_t)s1 * D))[lane];
        ax = fmaf(w0, u0.x, ax); ay = fmaf(w0, u0.y, ay);
        ax = fmaf(w1, u1.x, ax); ay = fmaf(w1, u1.y, ay);
    }
    if (i < end) {
        int s0 = srcs[i];
        float w0 = dis[s0];
        float2 u0 = ((const float2*)(hin + (size_t)s0 * D))[lane];
        ax = fmaf(w0, u0.x, ax); ay = fmaf(w0, u0.y, ay);
    }
    ((float2*)(hout + (size_t)n * D))[lane] = make_float2(dn * ax, dn * ay);
}

// node head: node_key, t1/t2 edge partial dots, node-side segment bins
__global__ __launch_bounds__(256) void node_kernel(
    const float* __restrict__ h, const float* __restrict__ bh1,
    const float* __restrict__ We, const float* __restrict__ Wn,
    const float* __restrict__ bnb, const int* __restrict__ batch,
    float* __restrict__ nkey_out, float* __restrict__ t1, float* __restrict__ t2,
    float* __restrict__ accN) {
    __shared__ float binK[NG], binE[NG], binZ[NG], binC[NG];
    const int tid = threadIdx.x;
    for (int i = tid; i < NG; i += 256) { binK[i] = 0.f; binE[i] = 0.f; binZ[i] = 0.f; binC[i] = 0.f; }
    __syncthreads();

    const int CHUNK = 98;
    int start = blockIdx.x * CHUNK;
    int end = min(start + CHUNK, NN);
    int wid = tid >> 6, lane = tid & 63;
    float bnb0 = bnb[0];

    float2 w1 = ((const float2*)We)[lane];
    float2 w2 = ((const float2*)(We + D))[lane];
    float2 wn = ((const float2*)Wn)[lane];
    float2 bb = ((const float2*)bh1)[lane];

    for (int n = start + wid; n < end; n += 4) {
        float2 v = ((const float2*)(h + (size_t)n * D))[lane];
        v.x += bb.x; v.y += bb.y;
        float s1 = v.x * w1.x + v.y * w1.y;
        float s2 = v.x * w2.x + v.y * w2.y;
        float s3 = v.x * wn.x + v.y * wn.y;
        for (int o = 32; o; o >>= 1) {
            s1 += __shfl_xor(s1, o);
            s2 += __shfl_xor(s2, o);
            s3 += __shfl_xor(s3, o);
        }
        if (lane == 0) {
            t1[n] = s1;
            t2[n] = s2;
            float nk = sigmoidf(s3 + bnb0);
            nkey_out[n] = nk;
            int g = batch[n];
            atomicAdd(&binK[g], nk);
            atomicAdd(&binE[g], 1.0f - nk);
            if (nk > 0.f) atomicAdd(&binZ[g], 1.0f);
            atomicAdd(&binC[g], 1.0f);
        }
    }
    __syncthreads();
    if (start < NN) {
        int glo = batch[start];
        int ghi = batch[end - 1];
        for (int g = glo + tid; g <= ghi; g += 256) {
            atomicAdd(&accN[g], binK[g]);
            atomicAdd(&accN[NG + g], binE[g]);
            atomicAdd(&accN[2 * NG + g], binZ[g]);
            atomicAdd(&accN[3 * NG + g], binC[g]);
        }
    }
}

// edge head: edge_key + edge-side segment bins
__global__ __launch_bounds__(256) void edge_kernel(
    const int* __restrict__ ei, const float* __restrict__ t1,
    const float* __restrict__ t2, const float* __restrict__ be,
    const int* __restrict__ batch, float* __restrict__ ekey_out,
    float* __restrict__ accE) {
    __shared__ float binK[NG], binE[NG], binZ[NG], binC[NG];
    const int tid = threadIdx.x;
    for (int i = tid; i < NG; i += 256) { binK[i] = 0.f; binE[i] = 0.f; binZ[i] = 0.f; binC[i] = 0.f; }
    __syncthreads();
    float be0 = be[0];
    int stride = gridDim.x * 256;
    for (int e = blockIdx.x * 256 + tid; e < NE; e += stride) {
        int r = ei[e];
        int c = ei[NE + e];
        float ek = sigmoidf(t1[r] + t2[c] + be0);
        ekey_out[e] = ek;
        int g = batch[r];
        atomicAdd(&binK[g], ek);
        atomicAdd(&binE[g], 1.0f - ek);
        if (ek > 0.f) atomicAdd(&binZ[g], 1.0f);
        atomicAdd(&binC[g], 1.0f);
    }
    __syncthreads();
    for (int g = tid; g < NG; g += 256) {
        if (binC[g] != 0.f) {
            atomicAdd(&accE[g], binK[g]);
            atomicAdd(&accE[NG + g], binE[g]);
            atomicAdd(&accE[2 * NG + g], binZ[g]);
            atomicAdd(&accE[3 * NG + g], binC[g]);
        }
    }
}

__global__ void final_kernel(const float* __restrict__ accN,
                             const float* __restrict__ accE,
                             float* __restrict__ out) {
    int g = blockIdx.x * 256 + threadIdx.x;
    if (g < NG) {
        out[O_NKN + g] = accN[g] + 1e-8f;
        out[O_NEN + g] = accN[NG + g] + 1e-8f;
        out[O_EKN + g] = accE[g] + 1e-8f;
        out[O_EEN + g] = accE[NG + g] + 1e-8f;
        out[O_NZN + g] = accN[2 * NG + g] / accN[3 * NG + g];
        out[O_NZE + g] = accE[2 * NG + g] / accE[3 * NG + g];
    }
}

extern "C" void kernel_launch(void* const* d_in, const int* in_sizes, int n_in,
                              void* d_out, int out_size, void* d_ws, size_t ws_size,
                              hipStream_t stream) {
    const float* x     = (const float*)d_in[0];
    const int*   ei    = (const int*)d_in[1];
    const int*   batch = (const int*)d_in[2];
    const float* W     = (const float*)d_in[4];
    const float* bh    = (const float*)d_in[5];   // [2][128]
    const float* gamma = (const float*)d_in[6];
    const float* beta  = (const float*)d_in[7];
    const float* mean  = (const float*)d_in[8];
    const float* var   = (const float*)d_in[9];
    const float* We    = (const float*)d_in[10];  // [256]
    const float* be    = (const float*)d_in[11];
    const float* Wn    = (const float*)d_in[12];  // [128]
    const float* bnb   = (const float*)d_in[13];

    float* ws  = (float*)d_ws;
    float* out = (float*)d_out;

    int*   deg  = (int*)(ws + OFF_DEG);
    int*   cnt  = (int*)(ws + OFF_CNT);
    float* accN = ws + OFF_ACCN;
    float* accE = ws + OFF_ACCE;
    float* dis  = ws + OFF_DIS;
    int*   colp = (int*)(ws + OFF_COLP);
    int*   cur  = (int*)(ws + OFF_CUR);
    int*   bsum = (int*)(ws + OFF_BSUM);
    int*   boff = (int*)(ws + OFF_BOFF);
    float* t1   = ws + OFF_T1;
    float* t2   = ws + OFF_T2;
    float* Wp   = ws + OFF_WP;
    float* bp   = ws + OFF_BP;
    float* hA   = ws + OFF_HA;
    float* hB   = ws + OFF_HB;

    hipMemsetAsync(d_ws, 0, (size_t)ZERO_FLOATS * sizeof(float), stream);

    prep_w<<<3, 128, 0, stream>>>(W, gamma, beta, mean, var, Wp, bp);
    degcnt_kernel<<<(NE + 255) / 256, 256, 0, stream>>>(ei, deg, cnt);
    dis_kernel<<<(NN + 255) / 256, 256, 0, stream>>>(deg, dis);

    // CSR build (by destination column)
    const int NB = (NN + 255) / 256;  // 196
    scan1<<<NB, 256, 0, stream>>>(cnt, colp, bsum);
    scan2<<<1, 256, 0, stream>>>(bsum, boff, NB);
    scan3<<<NB, 256, 0, stream>>>(colp, boff, cur);
    fill_kernel<<<(NE + 255) / 256, 256, 0, stream>>>(ei, cur, (int*)(ws + OFF_SRCS));

    // layer 0: hA = relu(x @ Wp0 + bp0)
    gemm128<false, true><<<782, 256, 0, stream>>>(x, Wp, bp, nullptr, hA);
    // layer 1 linear: hB = hA @ Wp1 + bp1
    gemm128<false, false><<<782, 256, 0, stream>>>(hA, Wp + D * D, bp + D, nullptr, hB);
    // propagate 1: hA = P(hB)
    prop_gather<<<12500, 256, 0, stream>>>(colp, cur, (int*)(ws + OFF_SRCS), dis, hB, hA);
    // layer 2 linear with fused relu(h + b_hidden[0]) on input
    gemm128<true, false><<<782, 256, 0, stream>>>(hA, Wp + 2 * D * D, bp + 2 * D, bh, hB);
    // propagate 2: hA = P(hB)
    prop_gather<<<12500, 256, 0, stream>>>(colp, cur, (int*)(ws + OFF_SRCS), dis, hB, hA);

    // heads (node_rep = hA + b_hidden[1], applied inline)
    node_kernel<<<512, 256, 0, stream>>>(hA, bh + D, We, Wn, bnb, batch,
                                         out + O_NKEY, t1, t2, accN);
    edge_kernel<<<256, 256, 0, stream>>>(ei, t1, t2, be, batch, out + O_EKEY, accE);
    final_kernel<<<2, 256, 0, stream>>>(accN, accE, out);
}

// Round 3
// 374.214 us; speedup vs baseline: 4.1470x; 1.2391x over previous
//
#include <hip/hip_runtime.h>
#include <cstddef>
#include <cstring>

#define NN 50000
#define NE 800000
#define D 128
#define NG 512
#define BN_EPS 1e-5f

typedef __bf16 bf16_t;
typedef __bf16 bf16x8 __attribute__((ext_vector_type(8)));
typedef float f32x4 __attribute__((ext_vector_type(4)));

// ---- workspace layout (float offsets) ----
#define OFF_DEG   0            // int[50048] row (out) degree
#define OFF_CNT   50048        // int[50048] col (in) degree
#define OFF_ACCN  100096       // float[4*512]
#define OFF_ACCE  102144       // float[4*512]
#define ZERO_FLOATS 104192     // zeroed region = [0, here)
#define OFF_DIS   104192       // float[50048]
#define OFF_COLP  154240       // int[50048]
#define OFF_CUR   204288       // int[50048]
#define OFF_BSUM  254336       // int[256]
#define OFF_BOFF  254592       // int[256]
#define OFF_T1    254848       // float[50048]
#define OFF_T2    304896       // float[50048]
#define OFF_BP    354944       // float[3*128 padded to 512]
#define OFF_WPT   355456       // bf16[3*128*128] transposed folded weights (24576 floats)
#define OFF_SRCS  380032       // int[800000]
#define OFF_HA32  1180032      // float[50000*128] final prop2 output (fp32 for heads)
#define OFF_HBFA  7580032      // bf16[50048*128]  (3203072 float slots)
#define OFF_HBFB  10783104     // bf16[50048*128]

// ---- output layout (float offsets in d_out) ----
#define O_NKEY 0
#define O_EKEY 50000
#define O_NKN  850000
#define O_NEN  850512
#define O_EKN  851024
#define O_EEN  851536
#define O_NZN  852048
#define O_NZE  852560

__device__ __forceinline__ float sigmoidf(float x) {
    return 1.0f / (1.0f + expf(-x));
}

__device__ __forceinline__ unsigned short f2bf_bits(float f) {
    bf16_t h = (bf16_t)f;
    unsigned short u;
    __builtin_memcpy(&u, &h, 2);
    return u;
}

__device__ __forceinline__ float bf_lo(unsigned int u) {
    return __uint_as_float(u << 16);
}
__device__ __forceinline__ float bf_hi(unsigned int u) {
    return __uint_as_float(u & 0xFFFF0000u);
}

// Fold BN into weights, transpose, cast bf16:
// Wpt[l][j][k] = bf16(a[k]*W[l][k][j]); bp[l][j] = sum_k c[k]*W[l][k][j]
__global__ void prep_w(const float* __restrict__ W, const float* __restrict__ gamma,
                       const float* __restrict__ beta, const float* __restrict__ mean,
                       const float* __restrict__ var, bf16_t* __restrict__ Wpt,
                       float* __restrict__ bp) {
    int l = blockIdx.x;
    int j = threadIdx.x;
    float acc = 0.f;
    for (int k = 0; k < D; ++k) {
        float a = gamma[l * D + k] * rsqrtf(var[l * D + k] + BN_EPS);
        float c = beta[l * D + k] - mean[l * D + k] * a;
        float w = W[l * D * D + k * D + j];
        Wpt[l * D * D + j * D + k] = (bf16_t)(a * w);
        acc = fmaf(c, w, acc);
    }
    bp[l * D + j] = acc;
}

__global__ void degcnt_kernel(const int* __restrict__ ei, int* __restrict__ deg,
                              int* __restrict__ cnt) {
    int e = blockIdx.x * 256 + threadIdx.x;
    if (e < NE) {
        atomicAdd(&deg[ei[e]], 1);
        atomicAdd(&cnt[ei[NE + e]], 1);
    }
}

__global__ void dis_kernel(const int* __restrict__ deg, float* __restrict__ dis) {
    int n = blockIdx.x * 256 + threadIdx.x;
    if (n < NN) dis[n] = rsqrtf((float)(deg[n] + 1));
}

// ---- 3-phase exclusive scan of cnt -> colptr ----
__global__ void scan1(const int* __restrict__ cnt, int* __restrict__ colp,
                      int* __restrict__ bsum) {
    __shared__ int s[256];
    int t = threadIdx.x;
    int i = blockIdx.x * 256 + t;
    int v = (i < NN) ? cnt[i] : 0;
    s[t] = v;
    __syncthreads();
    for (int o = 1; o < 256; o <<= 1) {
        int add = (t >= o) ? s[t - o] : 0;
        __syncthreads();
        s[t] += add;
        __syncthreads();
    }
    if (i < NN) colp[i] = s[t] - v;
    if (t == 255) bsum[blockIdx.x] = s[255];
}

__global__ void scan2(const int* __restrict__ bsum, int* __restrict__ boff, int nb) {
    __shared__ int s[256];
    int t = threadIdx.x;
    int v = (t < nb) ? bsum[t] : 0;
    s[t] = v;
    __syncthreads();
    for (int o = 1; o < 256; o <<= 1) {
        int add = (t >= o) ? s[t - o] : 0;
        __syncthreads();
        s[t] += add;
        __syncthreads();
    }
    boff[t] = s[t] - v;
}

__global__ void scan3(int* __restrict__ colp, const int* __restrict__ boff,
                      int* __restrict__ cur) {
    int i = blockIdx.x * 256 + threadIdx.x;
    if (i < NN) {
        int v = colp[i] + boff[i >> 8];
        colp[i] = v;
        cur[i] = v;
    }
}

__global__ void fill_kernel(const int* __restrict__ ei, int* __restrict__ cur,
                            int* __restrict__ srcs) {
    int e = blockIdx.x * 256 + threadIdx.x;
    if (e < NE) {
        int r = ei[e];
        int c = ei[NE + e];
        int pos = atomicAdd(&cur[c], 1);
        srcs[pos] = r;
    }
}

// MFMA bf16 GEMM: out[NNx128] = act(A[NNx128] @ B + bias). Bt is col-major bf16.
// Block = 256 thr = 4 waves; each wave does 16 rows x 128 cols.
// AMODE: 0 = A fp32 (convert in-register), 1 = A bf16.
template <int AMODE, bool ORELU>
__global__ __launch_bounds__(256) void gemm_mfma(const void* __restrict__ Aptr,
                                                 const bf16_t* __restrict__ Bt,
                                                 const float* __restrict__ bias,
                                                 bf16_t* __restrict__ out) {
    const int tid = threadIdx.x;
    const int wv = tid >> 6;
    const int lane = tid & 63;
    const int l15 = lane & 15;
    const int l4 = lane >> 4;
    const int row0 = blockIdx.x * 64 + wv * 16;

    // A fragments: A[row0 + l15][kk*32 + l4*8 + j]
    bf16x8 afrag[4];
    {
        int r = row0 + l15;
        int rc = (r < NN) ? r : (NN - 1);
#pragma unroll
        for (int kk = 0; kk < 4; ++kk) {
            int off = rc * D + kk * 32 + l4 * 8;
            if (AMODE == 0) {
                const float* A = (const float*)Aptr;
                float4 f0 = *(const float4*)(A + off);
                float4 f1 = *(const float4*)(A + off + 4);
                bf16x8 a;
                a[0] = (bf16_t)f0.x; a[1] = (bf16_t)f0.y;
                a[2] = (bf16_t)f0.z; a[3] = (bf16_t)f0.w;
                a[4] = (bf16_t)f1.x; a[5] = (bf16_t)f1.y;
                a[6] = (bf16_t)f1.z; a[7] = (bf16_t)f1.w;
                afrag[kk] = a;
            } else {
                const bf16_t* A = (const bf16_t*)Aptr;
                afrag[kk] = *(const bf16x8*)(A + off);
            }
        }
    }

    f32x4 acc[8];
#pragma unroll
    for (int n = 0; n < 8; ++n) acc[n] = (f32x4){0.f, 0.f, 0.f, 0.f};

#pragma unroll
    for (int n = 0; n < 8; ++n) {
#pragma unroll
        for (int kk = 0; kk < 4; ++kk) {
            bf16x8 bfrag = *(const bf16x8*)(Bt + (n * 16 + l15) * D + kk * 32 + l4 * 8);
            acc[n] = __builtin_amdgcn_mfma_f32_16x16x32_bf16(afrag[kk], bfrag, acc[n], 0, 0, 0);
        }
    }

    // C/D: row = row0 + l4*4 + r, col = n*16 + l15
#pragma unroll
    for (int n = 0; n < 8; ++n) {
        int col = n * 16 + l15;
        float bv = bias[col];
#pragma unroll
        for (int r = 0; r < 4; ++r) {
            int row = row0 + l4 * 4 + r;
            if (row < NN) {
                float v = acc[n][r] + bv;
                if (ORELU) v = fmaxf(v, 0.f);
                out[(size_t)row * D + col] = (bf16_t)v;
            }
        }
    }
}

// gather-form GCN propagate from bf16 h; one wave per destination node.
// POST 0: out bf16 = relu(v + bias[c]);  POST 1: out fp32 = v
template <int POST>
__global__ __launch_bounds__(256) void prop_gather(
    const int* __restrict__ colp, const int* __restrict__ cur,
    const int* __restrict__ srcs, const float* __restrict__ dis,
    const bf16_t* __restrict__ hin, void* __restrict__ hout,
    const float* __restrict__ bias) {
    int wid = blockIdx.x * 4 + (threadIdx.x >> 6);
    int lane = threadIdx.x & 63;
    if (wid >= NN) return;
    const int n = wid;
    const int start = colp[n];
    const int end = cur[n];
    const float dn = dis[n];
    unsigned int u = ((const unsigned int*)(hin + (size_t)n * D))[lane];
    float ax = dn * bf_lo(u), ay = dn * bf_hi(u);
    int i = start;
    for (; i + 1 < end; i += 2) {
        int s0 = srcs[i], s1 = srcs[i + 1];
        float w0 = dis[s0], w1 = dis[s1];
        unsigned int u0 = ((const unsigned int*)(hin + (size_t)s0 * D))[lane];
        unsigned int u1 = ((const unsigned int*)(hin + (size_t)s1 * D))[lane];
        ax = fmaf(w0, bf_lo(u0), ax); ay = fmaf(w0, bf_hi(u0), ay);
        ax = fmaf(w1, bf_lo(u1), ax); ay = fmaf(w1, bf_hi(u1), ay);
    }
    if (i < end) {
        int s0 = srcs[i];
        float w0 = dis[s0];
        unsigned int u0 = ((const unsigned int*)(hin + (size_t)s0 * D))[lane];
        ax = fmaf(w0, bf_lo(u0), ax); ay = fmaf(w0, bf_hi(u0), ay);
    }
    float vx = dn * ax, vy = dn * ay;
    if (POST == 0) {
        float2 bb = ((const float2*)bias)[lane];
        vx = fmaxf(vx + bb.x, 0.f);
        vy = fmaxf(vy + bb.y, 0.f);
        unsigned int pk = (unsigned int)f2bf_bits(vx) | ((unsigned int)f2bf_bits(vy) << 16);
        ((unsigned int*)((bf16_t*)hout + (size_t)n * D))[lane] = pk;
    } else {
        ((float2*)((float*)hout + (size_t)n * D))[lane] = make_float2(vx, vy);
    }
}

// node head: node_key, t1/t2 edge partial dots, node-side segment bins
__global__ __launch_bounds__(256) void node_kernel(
    const float* __restrict__ h, const float* __restrict__ bh1,
    const float* __restrict__ We, const float* __restrict__ Wn,
    const float* __restrict__ bnb, const int* __restrict__ batch,
    float* __restrict__ nkey_out, float* __restrict__ t1, float* __restrict__ t2,
    float* __restrict__ accN) {
    __shared__ float binK[NG], binE[NG], binZ[NG], binC[NG];
    const int tid = threadIdx.x;
    for (int i = tid; i < NG; i += 256) { binK[i] = 0.f; binE[i] = 0.f; binZ[i] = 0.f; binC[i] = 0.f; }
    __syncthreads();

    const int CHUNK = 98;
    int start = blockIdx.x * CHUNK;
    int end = min(start + CHUNK, NN);
    int wid = tid >> 6, lane = tid & 63;
    float bnb0 = bnb[0];

    float2 w1 = ((const float2*)We)[lane];
    float2 w2 = ((const float2*)(We + D))[lane];
    float2 wn = ((const float2*)Wn)[lane];
    float2 bb = ((const float2*)bh1)[lane];

    for (int n = start + wid; n < end; n += 4) {
        float2 v = ((const float2*)(h + (size_t)n * D))[lane];
        v.x += bb.x; v.y += bb.y;
        float s1 = v.x * w1.x + v.y * w1.y;
        float s2 = v.x * w2.x + v.y * w2.y;
        float s3 = v.x * wn.x + v.y * wn.y;
        for (int o = 32; o; o >>= 1) {
            s1 += __shfl_xor(s1, o);
            s2 += __shfl_xor(s2, o);
            s3 += __shfl_xor(s3, o);
        }
        if (lane == 0) {
            t1[n] = s1;
            t2[n] = s2;
            float nk = sigmoidf(s3 + bnb0);
            nkey_out[n] = nk;
            int g = batch[n];
            atomicAdd(&binK[g], nk);
            atomicAdd(&binE[g], 1.0f - nk);
            if (nk > 0.f) atomicAdd(&binZ[g], 1.0f);
            atomicAdd(&binC[g], 1.0f);
        }
    }
    __syncthreads();
    if (start < NN) {
        int glo = batch[start];
        int ghi = batch[end - 1];
        for (int g = glo + tid; g <= ghi; g += 256) {
            atomicAdd(&accN[g], binK[g]);
            atomicAdd(&accN[NG + g], binE[g]);
            atomicAdd(&accN[2 * NG + g], binZ[g]);
            atomicAdd(&accN[3 * NG + g], binC[g]);
        }
    }
}

__global__ __launch_bounds__(256) void edge_kernel(
    const int* __restrict__ ei, const float* __restrict__ t1,
    const float* __restrict__ t2, const float* __restrict__ be,
    const int* __restrict__ batch, float* __restrict__ ekey_out,
    float* __restrict__ accE) {
    __shared__ float binK[NG], binE[NG], binZ[NG], binC[NG];
    const int tid = threadIdx.x;
    for (int i = tid; i < NG; i += 256) { binK[i] = 0.f; binE[i] = 0.f; binZ[i] = 0.f; binC[i] = 0.f; }
    __syncthreads();
    float be0 = be[0];
    int stride = gridDim.x * 256;
    for (int e = blockIdx.x * 256 + tid; e < NE; e += stride) {
        int r = ei[e];
        int c = ei[NE + e];
        float ek = sigmoidf(t1[r] + t2[c] + be0);
        ekey_out[e] = ek;
        int g = batch[r];
        atomicAdd(&binK[g], ek);
        atomicAdd(&binE[g], 1.0f - ek);
        if (ek > 0.f) atomicAdd(&binZ[g], 1.0f);
        atomicAdd(&binC[g], 1.0f);
    }
    __syncthreads();
    for (int g = tid; g < NG; g += 256) {
        if (binC[g] != 0.f) {
            atomicAdd(&accE[g], binK[g]);
            atomicAdd(&accE[NG + g], binE[g]);
            atomicAdd(&accE[2 * NG + g], binZ[g]);
            atomicAdd(&accE[3 * NG + g], binC[g]);
        }
    }
}

__global__ void final_kernel(const float* __restrict__ accN,
                             const float* __restrict__ accE,
                             float* __restrict__ out) {
    int g = blockIdx.x * 256 + threadIdx.x;
    if (g < NG) {
        out[O_NKN + g] = accN[g] + 1e-8f;
        out[O_NEN + g] = accN[NG + g] + 1e-8f;
        out[O_EKN + g] = accE[g] + 1e-8f;
        out[O_EEN + g] = accE[NG + g] + 1e-8f;
        out[O_NZN + g] = accN[2 * NG + g] / accN[3 * NG + g];
        out[O_NZE + g] = accE[2 * NG + g] / accE[3 * NG + g];
    }
}

extern "C" void kernel_launch(void* const* d_in, const int* in_sizes, int n_in,
                              void* d_out, int out_size, void* d_ws, size_t ws_size,
                              hipStream_t stream) {
    const float* x     = (const float*)d_in[0];
    const int*   ei    = (const int*)d_in[1];
    const int*   batch = (const int*)d_in[2];
    const float* W     = (const float*)d_in[4];
    const float* bh    = (const float*)d_in[5];   // [2][128]
    const float* gamma = (const float*)d_in[6];
    const float* beta  = (const float*)d_in[7];
    const float* mean  = (const float*)d_in[8];
    const float* var   = (const float*)d_in[9];
    const float* We    = (const float*)d_in[10];
    const float* be    = (const float*)d_in[11];
    const float* Wn    = (const float*)d_in[12];
    const float* bnb   = (const float*)d_in[13];

    float* ws  = (float*)d_ws;
    float* out = (float*)d_out;

    int*    deg  = (int*)(ws + OFF_DEG);
    int*    cnt  = (int*)(ws + OFF_CNT);
    float*  accN = ws + OFF_ACCN;
    float*  accE = ws + OFF_ACCE;
    float*  dis  = ws + OFF_DIS;
    int*    colp = (int*)(ws + OFF_COLP);
    int*    cur  = (int*)(ws + OFF_CUR);
    int*    bsum = (int*)(ws + OFF_BSUM);
    int*    boff = (int*)(ws + OFF_BOFF);
    float*  t1   = ws + OFF_T1;
    float*  t2   = ws + OFF_T2;
    float*  bp   = ws + OFF_BP;
    bf16_t* Wpt  = (bf16_t*)(ws + OFF_WPT);
    int*    srcs = (int*)(ws + OFF_SRCS);
    float*  hA32 = ws + OFF_HA32;
    bf16_t* hbfA = (bf16_t*)(ws + OFF_HBFA);
    bf16_t* hbfB = (bf16_t*)(ws + OFF_HBFB);

    hipMemsetAsync(d_ws, 0, (size_t)ZERO_FLOATS * sizeof(float), stream);

    prep_w<<<3, 128, 0, stream>>>(W, gamma, beta, mean, var, Wpt, bp);
    degcnt_kernel<<<(NE + 255) / 256, 256, 0, stream>>>(ei, deg, cnt);
    dis_kernel<<<(NN + 255) / 256, 256, 0, stream>>>(deg, dis);

    const int NB = (NN + 255) / 256;  // 196
    scan1<<<NB, 256, 0, stream>>>(cnt, colp, bsum);
    scan2<<<1, 256, 0, stream>>>(bsum, boff, NB);
    scan3<<<NB, 256, 0, stream>>>(colp, boff, cur);
    fill_kernel<<<(NE + 255) / 256, 256, 0, stream>>>(ei, cur, srcs);

    const int GB = (NN + 63) / 64;  // 782
    // layer 0: hbfA = bf16(relu(x @ Wp0 + bp0))
    gemm_mfma<0, true><<<GB, 256, 0, stream>>>(x, Wpt, bp, hbfA);
    // layer 1 linear: hbfB = bf16(hbfA @ Wp1 + bp1)
    gemm_mfma<1, false><<<GB, 256, 0, stream>>>(hbfA, Wpt + D * D, bp + D, hbfB);
    // propagate 1 + fused relu(v + bh0): hbfA = bf16(relu(P(hbfB) + bh0))
    prop_gather<0><<<12500, 256, 0, stream>>>(colp, cur, srcs, dis, hbfB, hbfA, bh);
    // layer 2 linear: hbfB = bf16(hbfA @ Wp2 + bp2)
    gemm_mfma<1, false><<<GB, 256, 0, stream>>>(hbfA, Wpt + 2 * D * D, bp + 2 * D, hbfB);
    // propagate 2: hA32 = P(hbfB)  (fp32 for heads)
    prop_gather<1><<<12500, 256, 0, stream>>>(colp, cur, srcs, dis, hbfB, hA32, nullptr);

    node_kernel<<<512, 256, 0, stream>>>(hA32, bh + D, We, Wn, bnb, batch,
                                         out + O_NKEY, t1, t2, accN);
    edge_kernel<<<256, 256, 0, stream>>>(ei, t1, t2, be, batch, out + O_EKEY, accE);
    final_kernel<<<2, 256, 0, stream>>>(accN, accE, out);
}